// Round 13
// baseline (228.550 us; speedup 1.0000x reference)
//
#include <hip/hip_runtime.h>
#include <hip/hip_bf16.h>

typedef _Float16 f16;
typedef _Float16 f16x2 __attribute__((ext_vector_type(2)));
typedef _Float16 f16x4 __attribute__((ext_vector_type(4)));
typedef _Float16 f16x8 __attribute__((ext_vector_type(8)));
typedef float f32x4 __attribute__((ext_vector_type(4)));

#define B_  4
#define L_  2048
#define D_  4096
#define H_  8
#define BW_ 512
#define M_  (B_*L_)      // 8192
#define CHUNK 128
#define NCH (L_/CHUNK)   // 16
#define LOG2E 1.4426950408889634f

// workspace layout (bytes)
static const size_t OFF_WPK   = 0;                 // packed B frags: 8MB (both gates)
static const size_t OFF_MSP   = 8ull<<20;          // D_ f32 (16KB), pre-scaled by log2e
static const size_t OFF_XH    = 9ull<<20;          // M*D fp16 = 64MB
static const size_t OFF_YLAP  = 73ull<<20;         // M*D f16x2 (yloc,apfx) = 134MB
static const size_t OFF_SUMA  = 208ull<<20;        // B*NCH*D f32 = 1MB
static const size_t OFF_SUMY  = 209ull<<20;

__device__ __forceinline__ void gl16(const void* g, void* l) {
    __builtin_amdgcn_global_load_lds(
        (const __attribute__((address_space(1))) unsigned int*)g,
        (__attribute__((address_space(3))) unsigned int*)l, 16, 0, 0);
}

// ---------- prep (merged): wpack + msp2 (blocks 0..1023) | x->f16 (1024..3071) ----------
__global__ __launch_bounds__(256)
void prep_all(const float* __restrict__ w_in, const float* __restrict__ w_a,
              const float* __restrict__ a_param, const float* __restrict__ x,
              f16* __restrict__ wpk, float* __restrict__ msp2,
              f16* __restrict__ xh) {
    const int bid = blockIdx.x;
    const int tid = threadIdx.x;
    if (bid < 1024) {
        const int kt  = bid & 7;
        const int n32 = (bid >> 3) & 15;
        const int h   = bid >> 7;
        if (bid < 16) {                    // folded: msp2[d]
            int d = bid * 256 + tid;
            float v = a_param[d];
            msp2[d] = -8.f * log1pf(expf(v)) * LOG2E;
        }
#pragma unroll
        for (int q = 0; q < 2; ++q) {
            int slot = q * 256 + tid;      // 0..511
            int lane = slot & 63;
            int fidx = slot >> 6;          // g*4 + fn32*2 + kk2
            int g    = fidx >> 2;
            int fn   = (fidx >> 1) & 1;
            int kk2  = fidx & 1;
            int row = n32 * 32 + fn * 16 + (lane & 15);
            int col = kt * 64 + kk2 * 32 + ((lane >> 4) << 3);
            const float* src = (g ? w_a : w_in) + (size_t)h * BW_ * BW_;
            f16x8 v;
#pragma unroll
            for (int e = 0; e < 8; ++e)
                v[e] = (f16)src[(size_t)(col + e) * BW_ + row];
            size_t o = ((((size_t)(h * 16 + n32) * 8 + kt) * 8) + fidx) * 64 + lane;
            *(f16x8*)(wpk + o * 8) = v;
        }
    } else {
        size_t i = ((size_t)(bid - 1024) * 256 + tid) * 8;
        const size_t stride = (size_t)2048 * 256 * 8;
        for (; i < (size_t)M_ * D_; i += stride) {
            f32x4 v0 = *(const f32x4*)(x + i);
            f32x4 v1 = *(const f32x4*)(x + i + 4);
            f16x8 hv;
            hv[0] = (f16)v0.x; hv[1] = (f16)v0.y; hv[2] = (f16)v0.z; hv[3] = (f16)v0.w;
            hv[4] = (f16)v1.x; hv[5] = (f16)v1.y; hv[6] = (f16)v1.z; hv[7] = (f16)v1.w;
            *(f16x8*)(xh + i) = hv;
        }
    }
}

// ---------- fused gate GEMM + epilogue + chunk-local scan ----------
// BM=128 (= one scan chunk), BN=128, BKK=64, NT=8, 4 waves (2 wr x 2 wc),
// wave tile 64x64: 64 MFMA / 8 ds_read / 16 B-reg-loads per K-tile per wave
// -> MFMA-bound inner loop (R12 was VALU-issue-bound at BN=64).
// A: gl16 3-buf depth-2. B: single-buffered reg frags, issued BEFORE the A
// prefetch so counted vmcnt(4) covers both (FIFO retire order).
// K-tiles permuted (txo = (n0>>6)+2): tiles n0>>6 and n0>>6+1 land at slots
// 6,7 -> bufs 0,1 = epilogue xv (f16) for cols [n0, n0+128).
#define BM 128
#define BN 128
#define BKK 64
#define NT (BW_/BKK)     // 8 K-tiles
#define BUFB 16384       // bytes per A staging buffer

// LDS: staging bufs @0/16384/32768 (48K).  Post-loop overlay:
//  axn[128][132] f16x2 {om,xn} @0 (67584) | segA[4][132]f32 @67584 (2112) |
//  segY @69696 (2112) | rst_s[128]f32 @71808 (512) -> 72320
#define SMEM_BYTES 72320

__global__ __launch_bounds__(256, 2)
void gemm_gates(const f16*   __restrict__ xh,
                const int*   __restrict__ segpos,
                const f16*   __restrict__ wpk,
                const float* __restrict__ b_in,
                const float* __restrict__ b_a,
                const float* __restrict__ msp2,
                f16x2* __restrict__ ylap,
                float* __restrict__ sumA,
                float* __restrict__ sumY) {
    __shared__ __align__(16) char smem[SMEM_BYTES];
    f16x2* axn  = (f16x2*)smem;               // [128][132] {om, xn}
    float* segA = (float*)(smem + 67584);     // [4][132]
    float* segY = (float*)(smem + 69696);     // [4][132]
    float* rst_s= (float*)(smem + 71808);     // [128] (outside staging region)

    const int tid  = threadIdx.x;
    const int m0   = blockIdx.x * BM;         // m fastest: B panel L2-reused
    const int n0   = blockIdx.y * BN;
    const int h    = blockIdx.z;
    const int lane = tid & 63;
    const int wid  = tid >> 6;
    const int wr   = wid >> 1;
    const int wc   = wid & 1;

    f32x4 accX[4][4] = {};
    f32x4 accA[4][4] = {};

    // reset flags -> LDS (region untouched by staging)
    if (tid < BM) rst_s[tid] = (segpos[m0 + tid] == 0) ? 1.f : 0.f;

    // A staging map (source col pre-swizzled; LDS dest linear — m173/m201)
    const int grow  = lane >> 3;
    const int gcolS = (((lane & 7) ^ grow) << 3);
    const f16* aSrc = xh + (size_t)(m0 + wid * 32 + grow) * D_ + h * BW_ + gcolS;

    // B packed fragment bases: wave covers n32 groups (n0>>5)+wc*2 and +1
    const f16* wb0 = wpk + ((size_t)(h * 16) + (n0 >> 5) + wc * 2) * 32768;
    const f16* wb1 = wb0 + 32768;

    const int swz  = (lane & 7) << 3;        // read-side XOR (involution)
    const int kx   = (lane >> 4) << 3;       // 0,8,16,24
    const int arow = wr * 64 + (lane & 15);
    const int rowb = wr * 64 + ((lane >> 4) << 2);
    const int txo  = ((n0 >> 6) + 2) & (NT - 1); // tiles n0>>6,+1 -> slots 6,7

    f16x8 bfr[16];

#define STAGE_A(T)                                                            \
    {                                                                         \
        const int ktg = ((T) + txo) & (NT - 1);                               \
        f16* Asb = (f16*)(smem + ((T) % 3) * BUFB);                           \
        _Pragma("unroll")                                                     \
        for (int q = 0; q < 4; ++q)                                           \
            gl16(aSrc + ktg * BKK + (size_t)q * 8 * D_,                       \
                 &Asb[(wid * 32 + q * 8) * 64]);                              \
    }
#define LOAD_B(T)                                                             \
    {                                                                         \
        const int ktg = ((T) + txo) & (NT - 1);                               \
        _Pragma("unroll")                                                     \
        for (int fn = 0; fn < 4; ++fn) {                                      \
            const f16* tp = (fn < 2 ? wb0 : wb1) +                            \
                ((size_t)ktg * 8 + (fn & 1) * 2) * 512 + lane * 8;            \
            _Pragma("unroll")                                                 \
            for (int g = 0; g < 2; ++g)                                       \
                _Pragma("unroll")                                             \
                for (int kk2 = 0; kk2 < 2; ++kk2)                             \
                    bfr[fn * 4 + g * 2 + kk2] =                               \
                        *(const f16x8*)(tp + (g * 4 + kk2) * 512);            \
        }                                                                     \
    }

    // prologue
    STAGE_A(0);
    STAGE_A(1);

#pragma unroll
    for (int t = 0; t < NT; ++t) {
        LOAD_B(t);                           // 16 vm (older than A(t+2) in FIFO)
        if (t + 2 < NT) {
            STAGE_A(t + 2);                  // 4 vm
            asm volatile("s_waitcnt vmcnt(4)" ::: "memory"); // A(t),B(t) done
        } else {
            asm volatile("s_waitcnt vmcnt(0)" ::: "memory");
        }
        __builtin_amdgcn_s_barrier();        // all waves' A(t) visible
        __builtin_amdgcn_sched_barrier(0);

        const f16* Asb = (const f16*)(smem + (t % 3) * BUFB);
#pragma unroll
        for (int kk2 = 0; kk2 < 2; ++kk2) {
            const int kcolS = (kk2 * 32 + kx) ^ swz;
            f16x8 af[4];
#pragma unroll
            for (int fm = 0; fm < 4; ++fm)
                af[fm] = *(const f16x8*)&Asb[(arow + fm * 16) * 64 + kcolS];
#pragma unroll
            for (int fn = 0; fn < 4; ++fn) {
                f16x8 bx = bfr[fn * 4 + kk2];
                f16x8 ba = bfr[fn * 4 + 2 + kk2];
#pragma unroll
                for (int fm = 0; fm < 4; ++fm) {
                    accX[fm][fn] = __builtin_amdgcn_mfma_f32_16x16x32_f16(af[fm], bx, accX[fm][fn], 0, 0, 0);
                    accA[fm][fn] = __builtin_amdgcn_mfma_f32_16x16x32_f16(af[fm], ba, accA[fm][fn], 0, 0, 0);
                }
            }
        }
        __builtin_amdgcn_sched_barrier(0);
        __builtin_amdgcn_s_barrier();        // reads done before next overwrite
    }
#undef STAGE_A
#undef LOAD_B

    // ---- xv harvest: slot 6 -> buf0 (cols n0..n0+63, wc=0 waves),
    //      slot 7 -> buf1 (cols n0+64..n0+127, wc=1 waves). Wave-uniform.
    const f16* AsL = (const f16*)(smem + wc * BUFB);
    f16 xvv[4][4][4];
#pragma unroll
    for (int fn = 0; fn < 4; ++fn) {
        const int c5 = fn * 16 + (lane & 15);   // col within the 64-wide tile
#pragma unroll
        for (int fm = 0; fm < 4; ++fm)
#pragma unroll
            for (int reg = 0; reg < 4; ++reg) {
                const int rowt = rowb + fm * 16 + reg;
                xvv[fn][fm][reg] = AsL[rowt * 64 + (c5 ^ ((rowt & 7) << 3))];
            }
    }
    __syncthreads();   // xv in regs before overlay writes

    // ---- pass A: epilogue math -> packed {om = 1-a, xn} f16x2 in LDS ----
    // C/D layout: col = lane&15, row = (lane>>4)*4 + reg  [m89-verified]
    {
#pragma unroll
        for (int fn = 0; fn < 4; ++fn) {
            const int ctile = wc * 64 + fn * 16 + (lane & 15);
            const int d = h * BW_ + n0 + ctile;
            const float bx = b_in[d];
            const float ba = b_a[d];
            const float mspd = msp2[d];
#pragma unroll
            for (int fm = 0; fm < 4; ++fm) {
#pragma unroll
                for (int reg = 0; reg < 4; ++reg) {
                    const int rowt = rowb + fm * 16 + reg;       // 0..127
                    float gxl = accX[fm][fn][reg] + bx;
                    float gal = accA[fm][fn][reg] + ba;
                    float gx = __builtin_amdgcn_rcpf(1.f + __builtin_amdgcn_exp2f(-gxl * LOG2E));
                    float ga = __builtin_amdgcn_rcpf(1.f + __builtin_amdgcn_exp2f(-gal * LOG2E));
                    float a  = __builtin_amdgcn_exp2f(mspd * ga);
                    float a2 = a * a;                            // = exp(2*log_a)
                    float mult = __builtin_amdgcn_sqrtf(1.f + 1e-6f - a2);
                    float rv = rst_s[rowt];
                    a *= (1.f - rv);
                    mult = rv + (1.f - rv) * mult;
                    float xv = (float)xvv[fn][fm][reg];
                    f16x2 p;
                    p[0] = (f16)(1.f - a);
                    p[1] = (f16)(xv * gx * mult);
                    axn[rowt * 132 + ctile] = p;
                }
            }
        }
    }
    __syncthreads();

    // ---- pass B: per-segment (32-step) summaries; 512 (col,seg) pairs ----
    const int col = tid & 127;
    const int sg0 = tid >> 7;                 // wave-uniform (0 for waves 0-1)
#pragma unroll
    for (int ss = 0; ss < 2; ++ss) {
        const int seg = sg0 + ss * 2;
        float A = 1.f, yv = 0.f;
#pragma unroll 4
        for (int i = 0; i < 32; ++i) {
            f16x2 v = axn[(seg * 32 + i) * 132 + col];
            float a  = 1.f - (float)v[0];
            yv = fmaf(a, yv, (float)v[1]);
            A *= a;
        }
        segA[seg * 132 + col] = A;
        segY[seg * 132 + col] = yv;
    }
    __syncthreads();

    // ---- pass C: carry-in per segment, rewalk, write packed (yloc, apfx) ----
#pragma unroll
    for (int ss = 0; ss < 2; ++ss) {
        const int seg = sg0 + ss * 2;
        float cy = 0.f, pA = 1.f;
        for (int s = 0; s < seg; ++s) {
            float As_ = segA[s * 132 + col];
            cy = fmaf(As_, cy, segY[s * 132 + col]);
            pA *= As_;
        }
        float Arun = 1.f, yv = cy;
        const size_t obase = (size_t)(m0 + seg * 32) * D_ + h * BW_ + n0 + col;
#pragma unroll 4
        for (int i = 0; i < 32; ++i) {
            f16x2 v = axn[(seg * 32 + i) * 132 + col];
            float a  = 1.f - (float)v[0];
            yv = fmaf(a, yv, (float)v[1]);
            Arun *= a;
            f16x2 p;
            p[0] = (f16)yv;
            p[1] = (f16)(pA * Arun);
            ylap[obase + (size_t)i * D_] = p;
        }
        if (seg == 3) {
            const int bb = m0 >> 11;             // batch
            const int cc = (m0 & 2047) >> 7;     // chunk in batch
            size_t si = ((size_t)bb * NCH + cc) * D_ + h * BW_ + n0 + col;
            sumA[si] = pA * Arun;
            sumY[si] = yv;
        }
    }
}

// ---------- scan apply (carry scan folded in): y = yloc + h0 * apfx ----------
// grid (D/1024, NCH*4, B): each block redoes the <=15-step chunk-carry scan
// from L2-hot sums (2MB), then applies over its 32-row t-slice. Deletes the
// separate scan_mid kernel + carry buffer.
__global__ __launch_bounds__(256)
void scan_apply(const float* __restrict__ sumA, const float* __restrict__ sumY,
                const f16x2* __restrict__ ylap, float* __restrict__ y) {
    const int tid = threadIdx.x;
    const int d4  = (blockIdx.x * 256 + tid) * 4;
    const int c   = blockIdx.y >> 2;
    const int tq  = blockIdx.y & 3;
    const int b   = blockIdx.z;
    f32x4 h0 = {0.f, 0.f, 0.f, 0.f};
    for (int cp = 0; cp < c; ++cp) {
        size_t si = (((size_t)(b * NCH + cp)) << 12) + d4;
        f32x4 A = *(const f32x4*)(sumA + si);
        f32x4 Y = *(const f32x4*)(sumY + si);
        h0.x = fmaf(A.x, h0.x, Y.x);
        h0.y = fmaf(A.y, h0.y, Y.y);
        h0.z = fmaf(A.z, h0.z, Y.z);
        h0.w = fmaf(A.w, h0.w, Y.w);
    }
    size_t base = ((size_t)(b * L_ + c * CHUNK + tq * 32)) * D_ + d4;
#pragma unroll 4
    for (int i = 0; i < 32; ++i) {
        size_t o = base + (size_t)i * D_;
        f16x8 p = *(const f16x8*)(ylap + o);   // [y0,a0,y1,a1,y2,a2,y3,a3]
        f32x4 ov;
        ov.x = fmaf(h0.x, (float)p[1], (float)p[0]);
        ov.y = fmaf(h0.y, (float)p[3], (float)p[2]);
        ov.z = fmaf(h0.z, (float)p[5], (float)p[4]);
        ov.w = fmaf(h0.w, (float)p[7], (float)p[6]);
        *(f32x4*)(y + o) = ov;
    }
}

extern "C" void kernel_launch(void* const* d_in, const int* in_sizes, int n_in,
                              void* d_out, int out_size, void* d_ws, size_t ws_size,
                              hipStream_t stream) {
    const float* x       = (const float*)d_in[0];
    const int*   segpos  = (const int*)d_in[1];
    // d_in[2] = prev_h (unused by reference for L>1 path)
    const float* w_in    = (const float*)d_in[3];
    const float* b_in    = (const float*)d_in[4];
    const float* w_a     = (const float*)d_in[5];
    const float* b_a     = (const float*)d_in[6];
    const float* a_param = (const float*)d_in[7];

    float* y  = (float*)d_out;
    char*  ws = (char*)d_ws;
    f16*   wpk   = (f16*)(ws + OFF_WPK);
    float* msp2  = (float*)(ws + OFF_MSP);
    f16*   xh    = (f16*)(ws + OFF_XH);
    f16x2* ylap  = (f16x2*)(ws + OFF_YLAP);
    float* sumA  = (float*)(ws + OFF_SUMA);
    float* sumY  = (float*)(ws + OFF_SUMY);

    prep_all<<<dim3(3072), 256, 0, stream>>>(w_in, w_a, a_param, x, wpk, msp2, xh);
    gemm_gates<<<dim3(M_ / BM, BW_ / BN, H_), 256, 0, stream>>>(
        xh, segpos, wpk, b_in, b_a, msp2, ylap, sumA, sumY);
    scan_apply<<<dim3(D_ / 1024, NCH * 4, B_), 256, 0, stream>>>(sumA, sumY, ylap, y);
}

// Round 14
// 219.685 us; speedup vs baseline: 1.0404x; 1.0404x over previous
//
#include <hip/hip_runtime.h>
#include <hip/hip_bf16.h>

typedef _Float16 f16;
typedef _Float16 f16x8 __attribute__((ext_vector_type(8)));
typedef float f32x2 __attribute__((ext_vector_type(2)));
typedef float f32x4 __attribute__((ext_vector_type(4)));

#define B_  4
#define L_  2048
#define D_  4096
#define H_  8
#define BW_ 512
#define M_  (B_*L_)      // 8192
#define CHUNK 128
#define NCH (L_/CHUNK)   // 16
#define LOG2E 1.4426950408889634f

// workspace layout (bytes)
static const size_t OFF_WPK = 0;            // packed B frags: 8MB (both gates)
static const size_t OFF_MSP = 8ull<<20;     // D_ f32, pre-scaled by log2e
static const size_t OFF_XH  = 9ull<<20;     // M*D fp16 = 64MB

__device__ __forceinline__ void gl16(const void* g, void* l) {
    __builtin_amdgcn_global_load_lds(
        (const __attribute__((address_space(1))) unsigned int*)g,
        (__attribute__((address_space(3))) unsigned int*)l, 16, 0, 0);
}

// ---------- prep (merged): wpack + msp2 (blocks 0..1023) | x->f16 (1024..3071) ----------
__global__ __launch_bounds__(256)
void prep_all(const float* __restrict__ w_in, const float* __restrict__ w_a,
              const float* __restrict__ a_param, const float* __restrict__ x,
              f16* __restrict__ wpk, float* __restrict__ msp2,
              f16* __restrict__ xh) {
    const int bid = blockIdx.x;
    const int tid = threadIdx.x;
    if (bid < 1024) {
        const int kt  = bid & 7;
        const int n32 = (bid >> 3) & 15;
        const int h   = bid >> 7;
        if (bid < 16) {                    // folded: msp2[d]
            int d = bid * 256 + tid;
            float v = a_param[d];
            msp2[d] = -8.f * log1pf(expf(v)) * LOG2E;
        }
#pragma unroll
        for (int q = 0; q < 2; ++q) {
            int slot = q * 256 + tid;      // 0..511
            int lane = slot & 63;
            int fidx = slot >> 6;          // g*4 + fn*2 + kk2
            int g    = fidx >> 2;
            int fn   = (fidx >> 1) & 1;
            int kk2  = fidx & 1;
            int row = n32 * 32 + fn * 16 + (lane & 15);
            int col = kt * 64 + kk2 * 32 + ((lane >> 4) << 3);
            const float* src = (g ? w_a : w_in) + (size_t)h * BW_ * BW_;
            f16x8 v;
#pragma unroll
            for (int e = 0; e < 8; ++e)
                v[e] = (f16)src[(size_t)(col + e) * BW_ + row];
            size_t o = ((((size_t)(h * 16 + n32) * 8 + kt) * 8) + fidx) * 64 + lane;
            *(f16x8*)(wpk + o * 8) = v;
        }
    } else {
        size_t i = ((size_t)(bid - 1024) * 256 + tid) * 8;
        const size_t stride = (size_t)2048 * 256 * 8;
        for (; i < (size_t)M_ * D_; i += stride) {
            f32x4 v0 = *(const f32x4*)(x + i);
            f32x4 v1 = *(const f32x4*)(x + i + 4);
            f16x8 hv;
            hv[0] = (f16)v0.x; hv[1] = (f16)v0.y; hv[2] = (f16)v0.z; hv[3] = (f16)v0.w;
            hv[4] = (f16)v1.x; hv[5] = (f16)v1.y; hv[6] = (f16)v1.z; hv[7] = (f16)v1.w;
            *(f16x8*)(xh + i) = hv;
        }
    }
}

// ---------- persistent fused GEMM + epilogue + FULL-sequence scan ----------
// Grid (8 n0, 8 h, 4 b) = 256 blocks = 1/CU. Each block walks its batch's 16
// chunks SEQUENTIALLY; inter-chunk carry lives in LDS ping-pong (no cross-
// block sync — this is R7's fusion without R7's spin). Deletes ylap round-
// trip (268MB HBM) and the scan_apply kernel; y written f32 directly.
// K-loop per chunk = R12's structure: BM=128, BN=64, BKK=64, 4 waves (2x2),
// A via gl16 3-buf (slot t -> buf t%3), B via reg frags from L2-hot wpk,
// counted vmcnt(12); chunk entry drains vmcnt(0) (prefetch landed under
// previous chunk's tail). K-tiles permuted (txo): slot 6 = tile n0>>6 ->
// buf 0 holds epilogue xv after the loop.
#define BM 128
#define BN 64
#define BKK 64
#define NT (BW_/BKK)     // 8 K-tiles
#define BUFB 16384       // bytes per A staging buffer

// LDS map (no overlay; 117.2KB < m201's proven 128KB):
//  staging bufs @0/16384/32768 (49152) | axn[128][66] f32x2 {a,xn} @49152
//  (67584 -> ends 116736) | segA[4][72]f32 @116736 | segY @117888 |
//  rst_s[128]f32 @119040 | carry[2][64]f32 @119552 -> 120064
#define SMEM_BYTES 120064

__global__ __launch_bounds__(256, 1)
void gemm_scan(const f16*   __restrict__ xh,
               const int*   __restrict__ segpos,
               const f16*   __restrict__ wpk,
               const float* __restrict__ b_in,
               const float* __restrict__ b_a,
               const float* __restrict__ msp2,
               float* __restrict__ y) {
    __shared__ __align__(16) char smem[SMEM_BYTES];
    f32x2* axn   = (f32x2*)(smem + 49152);    // [128][66] {a, xn}
    float* segA  = (float*)(smem + 116736);   // [4][72]
    float* segY  = (float*)(smem + 117888);   // [4][72]
    float* rst_s = (float*)(smem + 119040);   // [128]
    float* carry = (float*)(smem + 119552);   // [2][64] ping-pong

    const int tid  = threadIdx.x;
    const int n0   = blockIdx.x * BN;
    const int h    = blockIdx.y;
    const int bb   = blockIdx.z;
    const int lane = tid & 63;
    const int wid  = tid >> 6;
    const int wr   = wid >> 1;
    const int wc   = wid & 1;

    if (tid < 64) { carry[tid] = 0.f; carry[64 + tid] = 0.f; }

    // A staging map (source col pre-swizzled; LDS dest linear — m173/m201)
    const int grow  = lane >> 3;
    const int gcolS = (((lane & 7) ^ grow) << 3);
    const f16* aBase = xh + (size_t)(bb * L_ + wid * 32 + grow) * D_ + h * BW_ + gcolS;

    // B packed fragment base for this wave: (h, n32 = n0/32 + wc)
    const f16* wbase = wpk + ((size_t)(h * 16) + (n0 >> 5) + wc) * 32768;

    const int swz  = (lane & 7) << 3;        // read-side XOR (involution)
    const int kx   = (lane >> 4) << 3;       // 0,8,16,24
    const int arow = wr * 64 + (lane & 15);
    const int rowb = wr * 64 + ((lane >> 4) << 2);
    const int txo  = ((n0 >> 6) + 2) & (NT - 1); // slot 6 = tile n0>>6 -> buf 0
    const int col  = tid & 63;               // tail column
    const int seg  = tid >> 6;                // tail segment (one per wave)

    f16x8 bfr[2][8];

#define STAGE_A(ASRC, SLOT)                                                   \
    {                                                                         \
        const int ktg = ((SLOT) + txo) & (NT - 1);                            \
        f16* Asb = (f16*)(smem + ((SLOT) % 3) * BUFB);                        \
        _Pragma("unroll")                                                     \
        for (int q = 0; q < 4; ++q)                                           \
            gl16((ASRC) + ktg * BKK + (size_t)q * 8 * D_,                     \
                 &Asb[(wid * 32 + q * 8) * 64]);                              \
    }
#define LOAD_B(SLOT)                                                          \
    {                                                                         \
        const int ktg = ((SLOT) + txo) & (NT - 1);                            \
        const f16* tp = wbase + (size_t)ktg * 4096;                           \
        _Pragma("unroll")                                                     \
        for (int j = 0; j < 8; ++j)                                           \
            bfr[(SLOT) & 1][j] = *(const f16x8*)(tp + j * 512 + lane * 8);    \
    }

    // block prologue: chunk 0 slots 0,1 + B(0)
    STAGE_A(aBase, 0);
    STAGE_A(aBase, 1);
    LOAD_B(0);

    for (int c = 0; c < NCH; ++c) {
        const int m0 = bb * L_ + c * CHUNK;
        const f16* aSrc  = aBase + (size_t)(c * CHUNK) * D_;
        const f16* aSrcN = aSrc + (size_t)CHUNK * D_;

        if (tid < BM) rst_s[tid] = (segpos[m0 + tid] == 0) ? 1.f : 0.f;

        f32x4 accX[4][2] = {};
        f32x4 accA[4][2] = {};

#pragma unroll
        for (int t = 0; t < NT; ++t) {
            if (t == 0)  // prefetch landed under previous tail; drains stores
                asm volatile("s_waitcnt vmcnt(0)" ::: "memory");
            if (t + 1 < NT) LOAD_B(t + 1);       // 8 vm
            if (t + 2 < NT) STAGE_A(aSrc, t + 2); // 4 vm
            if (t > 0) {
                if (t < NT - 1) asm volatile("s_waitcnt vmcnt(12)" ::: "memory");
                else            asm volatile("s_waitcnt vmcnt(0)"  ::: "memory");
            }
            __builtin_amdgcn_s_barrier();        // all waves' A(t) visible
            __builtin_amdgcn_sched_barrier(0);

            const f16* Asb = (const f16*)(smem + (t % 3) * BUFB);
#pragma unroll
            for (int kk2 = 0; kk2 < 2; ++kk2) {
                const int kcolS = (kk2 * 32 + kx) ^ swz;
                f16x8 af[4];
#pragma unroll
                for (int fm = 0; fm < 4; ++fm)
                    af[fm] = *(const f16x8*)&Asb[(arow + fm * 16) * 64 + kcolS];
#pragma unroll
                for (int fn = 0; fn < 2; ++fn) {
                    f16x8 bx = bfr[t & 1][fn * 2 + kk2];
                    f16x8 ba = bfr[t & 1][4 + fn * 2 + kk2];
#pragma unroll
                    for (int fm = 0; fm < 4; ++fm) {
                        accX[fm][fn] = __builtin_amdgcn_mfma_f32_16x16x32_f16(af[fm], bx, accX[fm][fn], 0, 0, 0);
                        accA[fm][fn] = __builtin_amdgcn_mfma_f32_16x16x32_f16(af[fm], ba, accA[fm][fn], 0, 0, 0);
                    }
                }
            }
            __builtin_amdgcn_sched_barrier(0);
            __builtin_amdgcn_s_barrier();        // reads done before overwrite
        }

        // ---- xv harvest: slot 6 (= tile n0>>6) lives in buf 0 ----
        const f16* AsL = (const f16*)smem;
        f16 xvv[2][4][4];
#pragma unroll
        for (int fn = 0; fn < 2; ++fn) {
            const int ctile = wc * 32 + fn * 16 + (lane & 15);
#pragma unroll
            for (int fm = 0; fm < 4; ++fm)
#pragma unroll
                for (int reg = 0; reg < 4; ++reg) {
                    const int rowt = rowb + fm * 16 + reg;
                    xvv[fn][fm][reg] = AsL[rowt * 64 + (ctile ^ ((rowt & 7) << 3))];
                }
        }
        __syncthreads();   // harvest done -> bufs 0,1 free for next chunk

        // cross-chunk prefetch: lands under this tail (~3000 cy of cover)
        if (c + 1 < NCH) {
            STAGE_A(aSrcN, 0);
            STAGE_A(aSrcN, 1);
            LOAD_B(0);
        }

        // ---- pass A: epilogue math -> {a, xn} f32x2 in LDS ----
        // C/D layout: col = lane&15, row = (lane>>4)*4 + reg  [m89-verified]
#pragma unroll
        for (int fn = 0; fn < 2; ++fn) {
            const int ctile = wc * 32 + fn * 16 + (lane & 15);
            const int d = h * BW_ + n0 + ctile;
            const float bx = b_in[d];
            const float ba = b_a[d];
            const float mspd = msp2[d];
#pragma unroll
            for (int fm = 0; fm < 4; ++fm) {
#pragma unroll
                for (int reg = 0; reg < 4; ++reg) {
                    const int rowt = rowb + fm * 16 + reg;       // 0..127
                    float gxl = accX[fm][fn][reg] + bx;
                    float gal = accA[fm][fn][reg] + ba;
                    float gx = __builtin_amdgcn_rcpf(1.f + __builtin_amdgcn_exp2f(-gxl * LOG2E));
                    float ga = __builtin_amdgcn_rcpf(1.f + __builtin_amdgcn_exp2f(-gal * LOG2E));
                    float a  = __builtin_amdgcn_exp2f(mspd * ga);
                    float a2 = a * a;                            // = exp(2*log_a)
                    float mult = __builtin_amdgcn_sqrtf(1.f + 1e-6f - a2);
                    float rv = rst_s[rowt];
                    a *= (1.f - rv);
                    mult = rv + (1.f - rv) * mult;
                    float xv = (float)xvv[fn][fm][reg];
                    f32x2 p;
                    p[0] = a;
                    p[1] = xv * gx * mult;
                    axn[rowt * 66 + ctile] = p;
                }
            }
        }
        __syncthreads();

        // ---- pass B: per-segment (32-step) summaries ----
        {
            float A = 1.f, yv = 0.f;
#pragma unroll 4
            for (int i = 0; i < 32; ++i) {
                f32x2 v = axn[(seg * 32 + i) * 66 + col];
                yv = fmaf(v[0], yv, v[1]);
                A *= v[0];
            }
            segA[seg * 72 + col] = A;
            segY[seg * 72 + col] = yv;
        }
        __syncthreads();

        // ---- pass C: carry-in, rewalk, write y (f32) direct; update carry ----
        {
            float yv = carry[(c & 1) * 64 + col];          // chunk carry-in
            for (int s = 0; s < seg; ++s)
                yv = fmaf(segA[s * 72 + col], yv, segY[s * 72 + col]);
            const size_t obase = (size_t)(m0 + seg * 32) * D_ + h * BW_ + n0 + col;
#pragma unroll 4
            for (int i = 0; i < 32; ++i) {
                f32x2 v = axn[(seg * 32 + i) * 66 + col];
                yv = fmaf(v[0], yv, v[1]);
                y[obase + (size_t)i * D_] = yv;
            }
            if (seg == 3)                                   // chunk-end h
                carry[((c + 1) & 1) * 64 + col] = yv;
        }
        // next chunk's K-loop barriers order carry write vs. next reads
    }
#undef STAGE_A
#undef LOAD_B
}

extern "C" void kernel_launch(void* const* d_in, const int* in_sizes, int n_in,
                              void* d_out, int out_size, void* d_ws, size_t ws_size,
                              hipStream_t stream) {
    const float* x       = (const float*)d_in[0];
    const int*   segpos  = (const int*)d_in[1];
    // d_in[2] = prev_h (unused by reference for L>1 path)
    const float* w_in    = (const float*)d_in[3];
    const float* b_in    = (const float*)d_in[4];
    const float* w_a     = (const float*)d_in[5];
    const float* b_a     = (const float*)d_in[6];
    const float* a_param = (const float*)d_in[7];

    float* y  = (float*)d_out;
    char*  ws = (char*)d_ws;
    f16*   wpk  = (f16*)(ws + OFF_WPK);
    float* msp2 = (float*)(ws + OFF_MSP);
    f16*   xh   = (f16*)(ws + OFF_XH);

    prep_all<<<dim3(3072), 256, 0, stream>>>(w_in, w_a, a_param, x, wpk, msp2, xh);
    gemm_scan<<<dim3(BW_ / BN, H_, B_), 256, 0, stream>>>(
        xh, segpos, wpk, b_in, b_a, msp2, y);
}

// Round 15
// 218.878 us; speedup vs baseline: 1.0442x; 1.0037x over previous
//
#include <hip/hip_runtime.h>
#include <hip/hip_bf16.h>

typedef _Float16 f16;
typedef _Float16 f16x8 __attribute__((ext_vector_type(8)));
typedef float f32x2 __attribute__((ext_vector_type(2)));
typedef float f32x4 __attribute__((ext_vector_type(4)));

#define B_  4
#define L_  2048
#define D_  4096
#define H_  8
#define BW_ 512
#define M_  (B_*L_)      // 8192
#define CHUNK 128
#define NCH (L_/CHUNK)   // 16
#define LOG2E 1.4426950408889634f

// workspace layout (bytes)
static const size_t OFF_WPK = 0;            // packed B frags: 8MB (both gates)
static const size_t OFF_MSP = 8ull<<20;     // D_ f32, pre-scaled by log2e
static const size_t OFF_XH  = 9ull<<20;     // M*D fp16 = 64MB

__device__ __forceinline__ void gl16(const void* g, void* l) {
    __builtin_amdgcn_global_load_lds(
        (const __attribute__((address_space(1))) unsigned int*)g,
        (__attribute__((address_space(3))) unsigned int*)l, 16, 0, 0);
}

// ---------- prep (merged): wpack + msp2 (blocks 0..1023) | x->f16 (1024..3071) ----------
__global__ __launch_bounds__(256)
void prep_all(const float* __restrict__ w_in, const float* __restrict__ w_a,
              const float* __restrict__ a_param, const float* __restrict__ x,
              f16* __restrict__ wpk, float* __restrict__ msp2,
              f16* __restrict__ xh) {
    const int bid = blockIdx.x;
    const int tid = threadIdx.x;
    if (bid < 1024) {
        const int kt  = bid & 7;
        const int n32 = (bid >> 3) & 15;
        const int h   = bid >> 7;
        if (bid < 16) {                    // folded: msp2[d]
            int d = bid * 256 + tid;
            float v = a_param[d];
            msp2[d] = -8.f * log1pf(expf(v)) * LOG2E;
        }
#pragma unroll
        for (int q = 0; q < 2; ++q) {
            int slot = q * 256 + tid;      // 0..511
            int lane = slot & 63;
            int fidx = slot >> 6;          // g*4 + fn*2 + kk2
            int g    = fidx >> 2;
            int fn   = (fidx >> 1) & 1;
            int kk2  = fidx & 1;
            int row = n32 * 32 + fn * 16 + (lane & 15);
            int col = kt * 64 + kk2 * 32 + ((lane >> 4) << 3);
            const float* src = (g ? w_a : w_in) + (size_t)h * BW_ * BW_;
            f16x8 v;
#pragma unroll
            for (int e = 0; e < 8; ++e)
                v[e] = (f16)src[(size_t)(col + e) * BW_ + row];
            size_t o = ((((size_t)(h * 16 + n32) * 8 + kt) * 8) + fidx) * 64 + lane;
            *(f16x8*)(wpk + o * 8) = v;
        }
    } else {
        size_t i = ((size_t)(bid - 1024) * 256 + tid) * 8;
        const size_t stride = (size_t)2048 * 256 * 8;
        for (; i < (size_t)M_ * D_; i += stride) {
            f32x4 v0 = *(const f32x4*)(x + i);
            f32x4 v1 = *(const f32x4*)(x + i + 4);
            f16x8 hv;
            hv[0] = (f16)v0.x; hv[1] = (f16)v0.y; hv[2] = (f16)v0.z; hv[3] = (f16)v0.w;
            hv[4] = (f16)v1.x; hv[5] = (f16)v1.y; hv[6] = (f16)v1.z; hv[7] = (f16)v1.w;
            *(f16x8*)(xh + i) = hv;
        }
    }
}

// ---------- persistent fused GEMM + epilogue + FULL-sequence scan ----------
// Grid (8 n0, 8 h, 4 b) = 256 blocks = 1/CU. Each block walks its batch's 16
// chunks SEQUENTIALLY; inter-chunk carry lives in LDS ping-pong (no cross-
// block sync — this is R7's fusion without R7's spin). Deletes ylap round-
// trip (268MB HBM) and the scan_apply kernel; y written f32 directly.
// K-loop per chunk = R12's structure: BM=128, BN=64, BKK=64, 4 waves (2x2),
// A via gl16 3-buf (slot t -> buf t%3), B via reg frags from L2-hot wpk,
// counted vmcnt(12); chunk entry drains vmcnt(0) (prefetch landed under
// previous chunk's tail). K-tiles permuted (txo): slot 6 = tile n0>>6 ->
// buf 0 holds epilogue xv after the loop.
#define BM 128
#define BN 64
#define BKK 64
#define NT (BW_/BKK)     // 8 K-tiles
#define BUFB 16384       // bytes per A staging buffer

// LDS map (no overlay; 117.2KB < m201's proven 128KB):
//  staging bufs @0/16384/32768 (49152) | axn[128][66] f32x2 {a,xn} @49152
//  (67584 -> ends 116736) | segA[4][72]f32 @116736 | segY @117888 |
//  rst_s[128]f32 @119040 | carry[2][64]f32 @119552 -> 120064
#define SMEM_BYTES 120064

__global__ __launch_bounds__(256, 1)
void gemm_scan(const f16*   __restrict__ xh,
               const int*   __restrict__ segpos,
               const f16*   __restrict__ wpk,
               const float* __restrict__ b_in,
               const float* __restrict__ b_a,
               const float* __restrict__ msp2,
               float* __restrict__ y) {
    __shared__ __align__(16) char smem[SMEM_BYTES];
    f32x2* axn   = (f32x2*)(smem + 49152);    // [128][66] {a, xn}
    float* segA  = (float*)(smem + 116736);   // [4][72]
    float* segY  = (float*)(smem + 117888);   // [4][72]
    float* rst_s = (float*)(smem + 119040);   // [128]
    float* carry = (float*)(smem + 119552);   // [2][64] ping-pong

    const int tid  = threadIdx.x;
    const int n0   = blockIdx.x * BN;
    const int h    = blockIdx.y;
    const int bb   = blockIdx.z;
    const int lane = tid & 63;
    const int wid  = tid >> 6;
    const int wr   = wid >> 1;
    const int wc   = wid & 1;

    if (tid < 64) { carry[tid] = 0.f; carry[64 + tid] = 0.f; }

    // A staging map (source col pre-swizzled; LDS dest linear — m173/m201)
    const int grow  = lane >> 3;
    const int gcolS = (((lane & 7) ^ grow) << 3);
    const f16* aBase = xh + (size_t)(bb * L_ + wid * 32 + grow) * D_ + h * BW_ + gcolS;

    // B packed fragment base for this wave: (h, n32 = n0/32 + wc)
    const f16* wbase = wpk + ((size_t)(h * 16) + (n0 >> 5) + wc) * 32768;

    const int swz  = (lane & 7) << 3;        // read-side XOR (involution)
    const int kx   = (lane >> 4) << 3;       // 0,8,16,24
    const int arow = wr * 64 + (lane & 15);
    const int rowb = wr * 64 + ((lane >> 4) << 2);
    const int txo  = ((n0 >> 6) + 2) & (NT - 1); // slot 6 = tile n0>>6 -> buf 0
    const int col  = tid & 63;               // tail column
    const int seg  = tid >> 6;                // tail segment (one per wave)

    f16x8 bfr[2][8];

#define STAGE_A(ASRC, SLOT)                                                   \
    {                                                                         \
        const int ktg = ((SLOT) + txo) & (NT - 1);                            \
        f16* Asb = (f16*)(smem + ((SLOT) % 3) * BUFB);                        \
        _Pragma("unroll")                                                     \
        for (int q = 0; q < 4; ++q)                                           \
            gl16((ASRC) + ktg * BKK + (size_t)q * 8 * D_,                     \
                 &Asb[(wid * 32 + q * 8) * 64]);                              \
    }
#define LOAD_B(SLOT)                                                          \
    {                                                                         \
        const int ktg = ((SLOT) + txo) & (NT - 1);                            \
        const f16* tp = wbase + (size_t)ktg * 4096;                           \
        _Pragma("unroll")                                                     \
        for (int j = 0; j < 8; ++j)                                           \
            bfr[(SLOT) & 1][j] = *(const f16x8*)(tp + j * 512 + lane * 8);    \
    }

    // block prologue: chunk 0 slots 0,1 + B(0)
    STAGE_A(aBase, 0);
    STAGE_A(aBase, 1);
    LOAD_B(0);

    for (int c = 0; c < NCH; ++c) {
        const int m0 = bb * L_ + c * CHUNK;
        const f16* aSrc  = aBase + (size_t)(c * CHUNK) * D_;
        const f16* aSrcN = aSrc + (size_t)CHUNK * D_;

        if (tid < BM) rst_s[tid] = (segpos[m0 + tid] == 0) ? 1.f : 0.f;

        f32x4 accX[4][2] = {};
        f32x4 accA[4][2] = {};

#pragma unroll
        for (int t = 0; t < NT; ++t) {
            if (t == 0)  // prefetch landed under previous tail; drains stores
                asm volatile("s_waitcnt vmcnt(0)" ::: "memory");
            if (t + 1 < NT) LOAD_B(t + 1);       // 8 vm
            if (t + 2 < NT) STAGE_A(aSrc, t + 2); // 4 vm
            if (t > 0) {
                if (t < NT - 1) asm volatile("s_waitcnt vmcnt(12)" ::: "memory");
                else            asm volatile("s_waitcnt vmcnt(0)"  ::: "memory");
            }
            __builtin_amdgcn_s_barrier();        // all waves' A(t) visible
            __builtin_amdgcn_sched_barrier(0);

            const f16* Asb = (const f16*)(smem + (t % 3) * BUFB);
#pragma unroll
            for (int kk2 = 0; kk2 < 2; ++kk2) {
                const int kcolS = (kk2 * 32 + kx) ^ swz;
                f16x8 af[4];
#pragma unroll
                for (int fm = 0; fm < 4; ++fm)
                    af[fm] = *(const f16x8*)&Asb[(arow + fm * 16) * 64 + kcolS];
#pragma unroll
                for (int fn = 0; fn < 2; ++fn) {
                    f16x8 bx = bfr[t & 1][fn * 2 + kk2];
                    f16x8 ba = bfr[t & 1][4 + fn * 2 + kk2];
#pragma unroll
                    for (int fm = 0; fm < 4; ++fm) {
                        accX[fm][fn] = __builtin_amdgcn_mfma_f32_16x16x32_f16(af[fm], bx, accX[fm][fn], 0, 0, 0);
                        accA[fm][fn] = __builtin_amdgcn_mfma_f32_16x16x32_f16(af[fm], ba, accA[fm][fn], 0, 0, 0);
                    }
                }
            }
            __builtin_amdgcn_sched_barrier(0);
            __builtin_amdgcn_s_barrier();        // reads done before overwrite
        }

        // ---- xv harvest: slot 6 (= tile n0>>6) lives in buf 0 ----
        const f16* AsL = (const f16*)smem;
        f16 xvv[2][4][4];
#pragma unroll
        for (int fn = 0; fn < 2; ++fn) {
            const int ctile = wc * 32 + fn * 16 + (lane & 15);
#pragma unroll
            for (int fm = 0; fm < 4; ++fm)
#pragma unroll
                for (int reg = 0; reg < 4; ++reg) {
                    const int rowt = rowb + fm * 16 + reg;
                    xvv[fn][fm][reg] = AsL[rowt * 64 + (ctile ^ ((rowt & 7) << 3))];
                }
        }
        __syncthreads();   // harvest done -> bufs 0,1 free for next chunk

        // cross-chunk prefetch: lands under this tail (~3000 cy of cover)
        if (c + 1 < NCH) {
            STAGE_A(aSrcN, 0);
            STAGE_A(aSrcN, 1);
            LOAD_B(0);
        }

        // ---- pass A: epilogue math -> {a, xn} f32x2 in LDS ----
        // C/D layout: col = lane&15, row = (lane>>4)*4 + reg  [m89-verified]
#pragma unroll
        for (int fn = 0; fn < 2; ++fn) {
            const int ctile = wc * 32 + fn * 16 + (lane & 15);
            const int d = h * BW_ + n0 + ctile;
            const float bx = b_in[d];
            const float ba = b_a[d];
            const float mspd = msp2[d];
#pragma unroll
            for (int fm = 0; fm < 4; ++fm) {
#pragma unroll
                for (int reg = 0; reg < 4; ++reg) {
                    const int rowt = rowb + fm * 16 + reg;       // 0..127
                    float gxl = accX[fm][fn][reg] + bx;
                    float gal = accA[fm][fn][reg] + ba;
                    float gx = __builtin_amdgcn_rcpf(1.f + __builtin_amdgcn_exp2f(-gxl * LOG2E));
                    float ga = __builtin_amdgcn_rcpf(1.f + __builtin_amdgcn_exp2f(-gal * LOG2E));
                    float a  = __builtin_amdgcn_exp2f(mspd * ga);
                    float a2 = a * a;                            // = exp(2*log_a)
                    float mult = __builtin_amdgcn_sqrtf(1.f + 1e-6f - a2);
                    float rv = rst_s[rowt];
                    a *= (1.f - rv);
                    mult = rv + (1.f - rv) * mult;
                    float xv = (float)xvv[fn][fm][reg];
                    f32x2 p;
                    p[0] = a;
                    p[1] = xv * gx * mult;
                    axn[rowt * 66 + ctile] = p;
                }
            }
        }
        __syncthreads();

        // ---- pass B: per-segment (32-step) summaries ----
        {
            float A = 1.f, yv = 0.f;
#pragma unroll 4
            for (int i = 0; i < 32; ++i) {
                f32x2 v = axn[(seg * 32 + i) * 66 + col];
                yv = fmaf(v[0], yv, v[1]);
                A *= v[0];
            }
            segA[seg * 72 + col] = A;
            segY[seg * 72 + col] = yv;
        }
        __syncthreads();

        // ---- pass C: carry-in, rewalk, write y (f32) direct; update carry ----
        {
            float yv = carry[(c & 1) * 64 + col];          // chunk carry-in
            for (int s = 0; s < seg; ++s)
                yv = fmaf(segA[s * 72 + col], yv, segY[s * 72 + col]);
            const size_t obase = (size_t)(m0 + seg * 32) * D_ + h * BW_ + n0 + col;
#pragma unroll 4
            for (int i = 0; i < 32; ++i) {
                f32x2 v = axn[(seg * 32 + i) * 66 + col];
                yv = fmaf(v[0], yv, v[1]);
                y[obase + (size_t)i * D_] = yv;
            }
            if (seg == 3)                                   // chunk-end h
                carry[((c + 1) & 1) * 64 + col] = yv;
        }
        // next chunk's K-loop barriers order carry write vs. next reads
    }
#undef STAGE_A
#undef LOAD_B
}

extern "C" void kernel_launch(void* const* d_in, const int* in_sizes, int n_in,
                              void* d_out, int out_size, void* d_ws, size_t ws_size,
                              hipStream_t stream) {
    const float* x       = (const float*)d_in[0];
    const int*   segpos  = (const int*)d_in[1];
    // d_in[2] = prev_h (unused by reference for L>1 path)
    const float* w_in    = (const float*)d_in[3];
    const float* b_in    = (const float*)d_in[4];
    const float* w_a     = (const float*)d_in[5];
    const float* b_a     = (const float*)d_in[6];
    const float* a_param = (const float*)d_in[7];

    float* y  = (float*)d_out;
    char*  ws = (char*)d_ws;
    f16*   wpk  = (f16*)(ws + OFF_WPK);
    float* msp2 = (float*)(ws + OFF_MSP);
    f16*   xh   = (f16*)(ws + OFF_XH);

    prep_all<<<dim3(3072), 256, 0, stream>>>(w_in, w_a, a_param, x, wpk, msp2, xh);
    gemm_scan<<<dim3(BW_ / BN, H_, B_), 256, 0, stream>>>(
        xh, segpos, wpk, b_in, b_a, msp2, y);
}

// Round 16
// 212.642 us; speedup vs baseline: 1.0748x; 1.0293x over previous
//
#include <hip/hip_runtime.h>
#include <hip/hip_bf16.h>

typedef _Float16 f16;
typedef _Float16 f16x2 __attribute__((ext_vector_type(2)));
typedef _Float16 f16x8 __attribute__((ext_vector_type(8)));
typedef float f32x4 __attribute__((ext_vector_type(4)));

#define B_  4
#define L_  2048
#define D_  4096
#define H_  8
#define BW_ 512
#define M_  (B_*L_)      // 8192
#define CHUNK 128
#define NCH (L_/CHUNK)   // 16
#define LOG2E 1.4426950408889634f

// workspace layout (bytes)
static const size_t OFF_WPK   = 0;                 // packed B frags: 8MB (both gates)
static const size_t OFF_MSP   = 8ull<<20;          // D_ f32, pre-scaled by log2e
static const size_t OFF_XH    = 9ull<<20;          // M*D fp16 = 64MB
static const size_t OFF_YLAP  = 73ull<<20;         // M*D f16x2 (yloc,apfx) = 134MB
static const size_t OFF_SUMA  = 208ull<<20;        // B*NCH*D f32 = 1MB
static const size_t OFF_SUMY  = 209ull<<20;

__device__ __forceinline__ void gl16(const void* g, void* l) {
    __builtin_amdgcn_global_load_lds(
        (const __attribute__((address_space(1))) unsigned int*)g,
        (__attribute__((address_space(3))) unsigned int*)l, 16, 0, 0);
}

// ---------- prep (merged): wpack + msp2 (blocks 0..1023) | x->f16 (1024..3071) ----------
__global__ __launch_bounds__(256)
void prep_all(const float* __restrict__ w_in, const float* __restrict__ w_a,
              const float* __restrict__ a_param, const float* __restrict__ x,
              f16* __restrict__ wpk, float* __restrict__ msp2,
              f16* __restrict__ xh) {
    const int bid = blockIdx.x;
    const int tid = threadIdx.x;
    if (bid < 1024) {
        const int kt  = bid & 7;
        const int n32 = (bid >> 3) & 15;
        const int h   = bid >> 7;
        if (bid < 16) {                    // folded: msp2[d]
            int d = bid * 256 + tid;
            float v = a_param[d];
            msp2[d] = -8.f * log1pf(expf(v)) * LOG2E;
        }
#pragma unroll
        for (int q = 0; q < 2; ++q) {
            int slot = q * 256 + tid;      // 0..511
            int lane = slot & 63;
            int fidx = slot >> 6;          // g*4 + fn*2 + kk2
            int g    = fidx >> 2;
            int fn   = (fidx >> 1) & 1;
            int kk2  = fidx & 1;
            int row = n32 * 32 + fn * 16 + (lane & 15);
            int col = kt * 64 + kk2 * 32 + ((lane >> 4) << 3);
            const float* src = (g ? w_a : w_in) + (size_t)h * BW_ * BW_;
            f16x8 v;
#pragma unroll
            for (int e = 0; e < 8; ++e)
                v[e] = (f16)src[(size_t)(col + e) * BW_ + row];
            size_t o = ((((size_t)(h * 16 + n32) * 8 + kt) * 8) + fidx) * 64 + lane;
            *(f16x8*)(wpk + o * 8) = v;
        }
    } else {
        size_t i = ((size_t)(bid - 1024) * 256 + tid) * 8;
        const size_t stride = (size_t)2048 * 256 * 8;
        for (; i < (size_t)M_ * D_; i += stride) {
            f32x4 v0 = *(const f32x4*)(x + i);
            f32x4 v1 = *(const f32x4*)(x + i + 4);
            f16x8 hv;
            hv[0] = (f16)v0.x; hv[1] = (f16)v0.y; hv[2] = (f16)v0.z; hv[3] = (f16)v0.w;
            hv[4] = (f16)v1.x; hv[5] = (f16)v1.y; hv[6] = (f16)v1.z; hv[7] = (f16)v1.w;
            *(f16x8*)(xh + i) = hv;
        }
    }
}

// ---------- fused gate GEMM + epilogue + chunk-local scan ----------
// BM=128 (= one scan chunk), BN=64, BKK=64, NT=8, 4 waves (2x2), 16x16x32 f16.
// K-loop: ONE barrier per tile (3-buf rotation makes the post-compute barrier
// redundant); explicit vmcnt(12) pre-barrier drains only A(t) (issued 2 iters
// ago); B(t+1) issued BEFORE A(t+2) so the implicit wait on B(t) regs leaves
// both prefetches in flight (R12's vmcnt(4) wrongly drained fresh B(t+1)).
// Epilogue stores {om=1-a, gm=gx*mult}; passes B/C read xv from buf0 (tile
// n0>>6, slot 6 via txo) — no scattered harvest, -16 VGPR.
#define BM 128
#define BN 64
#define BKK 64
#define NT (BW_/BKK)     // 8 K-tiles
#define BUFB 16384       // bytes per A staging buffer

// LDS: bufs @0/16384/32768 (48K; buf0 SURVIVES for xv).  Post-loop overlay
// (over buf1+buf2 only): axn[128][66] f16x2 {om,gm} @16384 (33792 -> 50176) |
// segA[4][72]f32 @50176 | segY @51328 | rst_s[128]f32 @52480 -> 52992
#define SMEM_BYTES 52992

__global__ __launch_bounds__(256, 2)
void gemm_gates(const f16*   __restrict__ xh,
                const int*   __restrict__ segpos,
                const f16*   __restrict__ wpk,
                const float* __restrict__ b_in,
                const float* __restrict__ b_a,
                const float* __restrict__ msp2,
                f16x2* __restrict__ ylap,
                float* __restrict__ sumA,
                float* __restrict__ sumY) {
    __shared__ __align__(16) char smem[SMEM_BYTES];
    f16x2* axn  = (f16x2*)(smem + 16384);     // [128][66] {om, gm}
    float* segA = (float*)(smem + 50176);     // [4][72]
    float* segY = (float*)(smem + 51328);     // [4][72]
    float* rst_s= (float*)(smem + 52480);     // [128]

    const int tid  = threadIdx.x;
    const int m0   = blockIdx.x * BM;         // m fastest (R6/R12 grid)
    const int n0   = blockIdx.y * BN;
    const int h    = blockIdx.z;
    const int lane = tid & 63;
    const int wid  = tid >> 6;
    const int wr   = wid >> 1;
    const int wc   = wid & 1;

    f32x4 accX[4][2] = {};
    f32x4 accA[4][2] = {};

    // reset flags -> LDS region untouched by staging (visible after barrier 0)
    if (tid < BM) rst_s[tid] = (segpos[m0 + tid] == 0) ? 1.f : 0.f;

    // A staging map (source col pre-swizzled; LDS dest linear — m173/m201)
    const int grow  = lane >> 3;
    const int gcolS = (((lane & 7) ^ grow) << 3);
    const f16* aSrc = xh + (size_t)(m0 + wid * 32 + grow) * D_ + h * BW_ + gcolS;

    // B packed fragment base for this wave: (h, n32 = n0/32 + wc)
    const f16* wbase = wpk + ((size_t)(h * 16) + (n0 >> 5) + wc) * 32768;

    const int swz  = (lane & 7) << 3;        // read-side XOR (involution)
    const int kx   = (lane >> 4) << 3;       // 0,8,16,24
    const int arow = wr * 64 + (lane & 15);
    const int rowb = wr * 64 + ((lane >> 4) << 2);
    const int txo  = ((n0 >> 6) + 2) & (NT - 1); // slot 6 = tile n0>>6 -> buf 0

    f16x8 bfr[2][8];

#define STAGE_A(T)                                                            \
    {                                                                         \
        const int ktg = ((T) + txo) & (NT - 1);                               \
        f16* Asb = (f16*)(smem + ((T) % 3) * BUFB);                           \
        _Pragma("unroll")                                                     \
        for (int q = 0; q < 4; ++q)                                           \
            gl16(aSrc + ktg * BKK + (size_t)q * 8 * D_,                       \
                 &Asb[(wid * 32 + q * 8) * 64]);                              \
    }
#define LOAD_B(T)                                                             \
    {                                                                         \
        const int ktg = ((T) + txo) & (NT - 1);                               \
        const f16* tp = wbase + (size_t)ktg * 4096;                           \
        _Pragma("unroll")                                                     \
        for (int j = 0; j < 8; ++j)                                           \
            bfr[(T) & 1][j] = *(const f16x8*)(tp + j * 512 + lane * 8);       \
    }

    // prologue: B(0) oldest, then A(0), A(1)
    LOAD_B(0);
    STAGE_A(0);
    STAGE_A(1);

#pragma unroll
    for (int t = 0; t < NT; ++t) {
        // explicit pre-barrier wait: drain A(t) (+B(0) at t=0); keep
        // A(t+1)[4] (+B(t)[8] for t>0) in flight
        if (t == 0)          asm volatile("s_waitcnt vmcnt(4)"  ::: "memory");
        else if (t < NT - 1) asm volatile("s_waitcnt vmcnt(12)" ::: "memory");
        else                 asm volatile("s_waitcnt vmcnt(8)"  ::: "memory");
        __builtin_amdgcn_s_barrier();        // all waves' A(t) visible
        // issue next prefetches: B before A (FIFO: implicit wait on B(t)
        // regs then leaves B(t+1)+A(t+2) flying)
        if (t + 1 < NT) LOAD_B(t + 1);       // 8 vm
        if (t + 2 < NT) STAGE_A(t + 2);      // 4 vm
        __builtin_amdgcn_sched_barrier(0);   // pin issues before compute

        const f16* Asb = (const f16*)(smem + (t % 3) * BUFB);
#pragma unroll
        for (int kk2 = 0; kk2 < 2; ++kk2) {
            const int kcolS = (kk2 * 32 + kx) ^ swz;
            f16x8 af[4];
#pragma unroll
            for (int fm = 0; fm < 4; ++fm)
                af[fm] = *(const f16x8*)&Asb[(arow + fm * 16) * 64 + kcolS];
#pragma unroll
            for (int fn = 0; fn < 2; ++fn) {
                f16x8 bx = bfr[t & 1][fn * 2 + kk2];
                f16x8 ba = bfr[t & 1][4 + fn * 2 + kk2];
#pragma unroll
                for (int fm = 0; fm < 4; ++fm) {
                    accX[fm][fn] = __builtin_amdgcn_mfma_f32_16x16x32_f16(af[fm], bx, accX[fm][fn], 0, 0, 0);
                    accA[fm][fn] = __builtin_amdgcn_mfma_f32_16x16x32_f16(af[fm], ba, accA[fm][fn], 0, 0, 0);
                }
            }
        }
        // no second barrier: 3-buf rotation + read-before-MFMA ordering make
        // the next iteration's gl16 overwrite race-free
    }
#undef STAGE_A
#undef LOAD_B

    __syncthreads();   // all compute reads of buf1/buf2 done before overlay

    // ---- pass A: epilogue math -> packed {om = 1-a, gm = gx*mult} in LDS ----
    // C/D layout: col = lane&15, row = (lane>>4)*4 + reg  [m89-verified]
    {
#pragma unroll
        for (int fn = 0; fn < 2; ++fn) {
            const int ctile = wc * 32 + fn * 16 + (lane & 15);
            const int d = h * BW_ + n0 + ctile;
            const float bx = b_in[d];
            const float ba = b_a[d];
            const float mspd = msp2[d];
#pragma unroll
            for (int fm = 0; fm < 4; ++fm) {
#pragma unroll
                for (int reg = 0; reg < 4; ++reg) {
                    const int rowt = rowb + fm * 16 + reg;       // 0..127
                    float gxl = accX[fm][fn][reg] + bx;
                    float gal = accA[fm][fn][reg] + ba;
                    float gx = __builtin_amdgcn_rcpf(1.f + __builtin_amdgcn_exp2f(-gxl * LOG2E));
                    float ga = __builtin_amdgcn_rcpf(1.f + __builtin_amdgcn_exp2f(-gal * LOG2E));
                    float a  = __builtin_amdgcn_exp2f(mspd * ga);
                    float a2 = a * a;                            // = exp(2*log_a)
                    float mult = __builtin_amdgcn_sqrtf(1.f + 1e-6f - a2);
                    float rv = rst_s[rowt];
                    a *= (1.f - rv);
                    mult = rv + (1.f - rv) * mult;
                    f16x2 p;
                    p[0] = (f16)(1.f - a);
                    p[1] = (f16)(gx * mult);
                    axn[rowt * 66 + ctile] = p;
                }
            }
        }
    }
    __syncthreads();

    // ---- pass B: per-segment (32-step) summaries; xv from surviving buf0 ----
    const f16* As0 = (const f16*)smem;        // tile n0>>6: cols [n0, n0+64)
    const int col = tid & 63;
    const int seg = tid >> 6;
    {
        float A = 1.f, yv = 0.f;
#pragma unroll 4
        for (int i = 0; i < 32; ++i) {
            const int t = seg * 32 + i;
            f16x2 v = axn[t * 66 + col];
            float a  = 1.f - (float)v[0];
            float xv = (float)As0[t * 64 + (col ^ ((t & 7) << 3))];
            yv = fmaf(a, yv, xv * (float)v[1]);
            A *= a;
        }
        segA[seg * 72 + col] = A;
        segY[seg * 72 + col] = yv;
    }
    __syncthreads();

    // ---- pass C: carry-in per segment, rewalk, write packed (yloc, apfx) ----
    {
        float cy = 0.f, pA = 1.f;
        for (int s = 0; s < seg; ++s) {
            float As_ = segA[s * 72 + col];
            cy = fmaf(As_, cy, segY[s * 72 + col]);
            pA *= As_;
        }
        float Arun = 1.f, yv = cy;
        const size_t obase = (size_t)(m0 + seg * 32) * D_ + h * BW_ + n0 + col;
#pragma unroll 4
        for (int i = 0; i < 32; ++i) {
            const int t = seg * 32 + i;
            f16x2 v = axn[t * 66 + col];
            float a  = 1.f - (float)v[0];
            float xv = (float)As0[t * 64 + (col ^ ((t & 7) << 3))];
            yv = fmaf(a, yv, xv * (float)v[1]);
            Arun *= a;
            f16x2 p;
            p[0] = (f16)yv;
            p[1] = (f16)(pA * Arun);
            ylap[obase + (size_t)i * D_] = p;
        }
        if (seg == 3) {
            const int bb = m0 >> 11;             // batch
            const int cc = (m0 & 2047) >> 7;     // chunk in batch
            size_t si = ((size_t)bb * NCH + cc) * D_ + h * BW_ + n0 + col;
            sumA[si] = pA * Arun;
            sumY[si] = yv;
        }
    }
}

// ---------- scan apply (carry scan folded in): y = yloc + h0 * apfx ----------
__global__ __launch_bounds__(256)
void scan_apply(const float* __restrict__ sumA, const float* __restrict__ sumY,
                const f16x2* __restrict__ ylap, float* __restrict__ y) {
    const int tid = threadIdx.x;
    const int d4  = (blockIdx.x * 256 + tid) * 4;
    const int c   = blockIdx.y >> 2;
    const int tq  = blockIdx.y & 3;
    const int b   = blockIdx.z;
    f32x4 h0 = {0.f, 0.f, 0.f, 0.f};
    for (int cp = 0; cp < c; ++cp) {
        size_t si = (((size_t)(b * NCH + cp)) << 12) + d4;
        f32x4 A = *(const f32x4*)(sumA + si);
        f32x4 Y = *(const f32x4*)(sumY + si);
        h0.x = fmaf(A.x, h0.x, Y.x);
        h0.y = fmaf(A.y, h0.y, Y.y);
        h0.z = fmaf(A.z, h0.z, Y.z);
        h0.w = fmaf(A.w, h0.w, Y.w);
    }
    size_t base = ((size_t)(b * L_ + c * CHUNK + tq * 32)) * D_ + d4;
#pragma unroll 4
    for (int i = 0; i < 32; ++i) {
        size_t o = base + (size_t)i * D_;
        f16x8 p = *(const f16x8*)(ylap + o);   // [y0,a0,y1,a1,y2,a2,y3,a3]
        f32x4 ov;
        ov.x = fmaf(h0.x, (float)p[1], (float)p[0]);
        ov.y = fmaf(h0.y, (float)p[3], (float)p[2]);
        ov.z = fmaf(h0.z, (float)p[5], (float)p[4]);
        ov.w = fmaf(h0.w, (float)p[7], (float)p[6]);
        *(f32x4*)(y + o) = ov;
    }
}

extern "C" void kernel_launch(void* const* d_in, const int* in_sizes, int n_in,
                              void* d_out, int out_size, void* d_ws, size_t ws_size,
                              hipStream_t stream) {
    const float* x       = (const float*)d_in[0];
    const int*   segpos  = (const int*)d_in[1];
    // d_in[2] = prev_h (unused by reference for L>1 path)
    const float* w_in    = (const float*)d_in[3];
    const float* b_in    = (const float*)d_in[4];
    const float* w_a     = (const float*)d_in[5];
    const float* b_a     = (const float*)d_in[6];
    const float* a_param = (const float*)d_in[7];

    float* y  = (float*)d_out;
    char*  ws = (char*)d_ws;
    f16*   wpk   = (f16*)(ws + OFF_WPK);
    float* msp2  = (float*)(ws + OFF_MSP);
    f16*   xh    = (f16*)(ws + OFF_XH);
    f16x2* ylap  = (f16x2*)(ws + OFF_YLAP);
    float* sumA  = (float*)(ws + OFF_SUMA);
    float* sumY  = (float*)(ws + OFF_SUMY);

    prep_all<<<dim3(3072), 256, 0, stream>>>(w_in, w_a, a_param, x, wpk, msp2, xh);
    gemm_gates<<<dim3(M_ / BM, BW_ / BN, H_), 256, 0, stream>>>(
        xh, segpos, wpk, b_in, b_a, msp2, ylap, sumA, sumY);
    scan_apply<<<dim3(D_ / 1024, NCH * 4, B_), 256, 0, stream>>>(sumA, sumY, ylap, y);
}